// Round 6
// baseline (183.559 us; speedup 1.0000x reference)
//
#include <hip/hip_runtime.h>
#include <stdint.h>

// ---------------------------------------------------------------------------
// MaskedAttentionHead: B=4, S=2048, d_model=1024, d_k=64
// R6: proj rebuilt with plain per-lane loads (no glds: R5 showed per-wave
// glds bursts cap at ~1 B/cyc -> 2.3 TB/s consumed regardless of structure).
// BW comes from wave count: 4-way K-split per 256-thr block -> 24 waves/CU,
// each keeping ~2 KB of float4 loads in flight; LDS combine epilogue (R3's,
// known-correct). attn/wcvt unchanged from R5 (attn still unprofiled).
// ---------------------------------------------------------------------------

typedef __bf16 bf16x8 __attribute__((ext_vector_type(8)));
typedef float  f32x4  __attribute__((ext_vector_type(4)));
typedef unsigned short u16;
typedef unsigned int   u32;

__device__ __forceinline__ u16 f2bf(float f) {
  u32 u = __float_as_uint(f);
  u += 0x7fffu + ((u >> 16) & 1u);          // round-to-nearest-even
  return (u16)(u >> 16);
}

union BF8 { bf16x8 v; u16 u[8]; };

__device__ __forceinline__ bf16x8 pack8(float4 a, float4 b) {
  BF8 r;
  r.u[0] = f2bf(a.x); r.u[1] = f2bf(a.y); r.u[2] = f2bf(a.z); r.u[3] = f2bf(a.w);
  r.u[4] = f2bf(b.x); r.u[5] = f2bf(b.y); r.u[6] = f2bf(b.z); r.u[7] = f2bf(b.w);
  return r.v;
}

// --------------------------- W fp32 -> bf16 --------------------------------
__global__ __launch_bounds__(256) void wcvt_kernel(
    const float* __restrict__ Wq, const float* __restrict__ Wk,
    const float* __restrict__ Wv, u16* __restrict__ Wbf) {
  int i = (blockIdx.x * 256 + threadIdx.x) * 4;   // 3*64*1024 = 196608 total
  const float* src = (i < 65536) ? Wq : (i < 131072) ? Wk : Wv;
  int off = i & 65535;
  float4 f = *(const float4*)(src + off);
  *(ushort4*)(Wbf + i) = make_ushort4(f2bf(f.x), f2bf(f.y), f2bf(f.z), f2bf(f.w));
}

// --------------------------- projections -----------------------------------
// grid (512,3), block 256 (4 waves), 6 blocks/CU. Block owns 16 rows; wave w
// owns k-slab [w*256,w*256+256): 8 k-steps of (2 float4 A-loads + 4 bf16x8
// W-loads + 4 MFMA), 1-step software pipeline, no barriers in the loop.
// A-loads are 16x64B-segment requests = same L2 cost as coalesced. Combine
// 4 k-partials via 16-KB LDS at the end (2 barriers total).
__global__ __launch_bounds__(256, 6) void proj_kernel(
    const float* __restrict__ q, const float* __restrict__ k,
    const float* __restrict__ v, const u16* __restrict__ Wbf,
    u16* __restrict__ qh, u16* __restrict__ kh, u16* __restrict__ vhT) {
  __shared__ float os[4][16][64];            // 16 KB combine buffer
  const int tid = threadIdx.x;
  const int lane = tid & 63, w = tid >> 6;
  const int c16 = lane & 15, quad = lane >> 4;
  const int which = blockIdx.y;
  const int r0 = blockIdx.x * 16;
  const float* X = (which == 0) ? q : (which == 1) ? k : v;

  const float* xp = X + (size_t)(r0 + c16) * 1024 + w * 256 + quad * 8;
  const u16* wp = Wbf + which * 65536 + (size_t)c16 * 1024 + w * 256 + quad * 8;

  f32x4 acc[4];
#pragma unroll
  for (int nt = 0; nt < 4; nt++)
#pragma unroll
    for (int j = 0; j < 4; j++) acc[nt][j] = 0.0f;

  // ---- software pipeline: stage ks+1 while MFMA ks ----
  float4 a0c = *(const float4*)xp;
  float4 a1c = *(const float4*)(xp + 4);
  bf16x8 wc[4];
#pragma unroll
  for (int nt = 0; nt < 4; nt++) wc[nt] = *(const bf16x8*)(wp + nt * 16384);

#pragma unroll
  for (int ks = 0; ks < 8; ks++) {
    float4 a0n, a1n;
    bf16x8 wn[4];
    if (ks < 7) {
      a0n = *(const float4*)(xp + (ks + 1) * 32);
      a1n = *(const float4*)(xp + (ks + 1) * 32 + 4);
#pragma unroll
      for (int nt = 0; nt < 4; nt++)
        wn[nt] = *(const bf16x8*)(wp + nt * 16384 + (ks + 1) * 32);
    }
    bf16x8 af = pack8(a0c, a1c);
#pragma unroll
    for (int nt = 0; nt < 4; nt++)
      acc[nt] = __builtin_amdgcn_mfma_f32_16x16x32_bf16(af, wc[nt], acc[nt], 0, 0, 0);
    a0c = a0n; a1c = a1n;
#pragma unroll
    for (int nt = 0; nt < 4; nt++) wc[nt] = wn[nt];
  }

  // ---- publish partials (C/D: row m = quad*4+rr, col n = nt*16+c16) ----
#pragma unroll
  for (int nt = 0; nt < 4; nt++)
#pragma unroll
    for (int rr = 0; rr < 4; rr++)
      os[w][quad * 4 + rr][nt * 16 + c16] = acc[nt][rr];
  __syncthreads();

  // ---- combine 4 k-partials, store ----
  if (which == 2) {
    const int col = tid >> 2, s4 = (tid & 3) * 4;
    float s[4];
#pragma unroll
    for (int rr = 0; rr < 4; rr++)
      s[rr] = os[0][s4 + rr][col] + os[1][s4 + rr][col] +
              os[2][s4 + rr][col] + os[3][s4 + rr][col];
    const int bb = r0 >> 11, s0 = (r0 & 2047) + s4;
    ushort4 pk = make_ushort4(f2bf(s[0]), f2bf(s[1]), f2bf(s[2]), f2bf(s[3]));
    *(ushort4*)(vhT + ((size_t)bb * 64 + col) * 2048 + s0) = pk;
  } else {
    u16* out = (which == 0) ? qh : kh;
    const int row = tid >> 4, c4 = (tid & 15) * 4;
    float s[4];
#pragma unroll
    for (int j = 0; j < 4; j++)
      s[j] = os[0][row][c4 + j] + os[1][row][c4 + j] +
             os[2][row][c4 + j] + os[3][row][c4 + j];
    ushort4 pk = make_ushort4(f2bf(s[0]), f2bf(s[1]), f2bf(s[2]), f2bf(s[3]));
    *(ushort4*)(out + (size_t)(r0 + row) * 64 + c4) = pk;
  }
}

// --------------------------- flash attention --------------------------------
// grid (128,4), block 512 (8 waves, kv-split 8). Transposed math:
//   S^T[kv][q] = K Q^T  (A=K-frag, B=Q-frag, both natural row-major)
//   O^T[d][q]  = V^T P^T (A=vhT-frag, B=P-frag from packed LDS)
// Mask scale is per-column q = c16 -> one scalar/lane. No kv-loop barriers.
__global__ __launch_bounds__(512, 4) void attn_kernel(
    const u16* __restrict__ qh, const u16* __restrict__ kh,
    const u16* __restrict__ vhT, const float* __restrict__ m,
    float* __restrict__ y) {
  __shared__ float Os[8][64][17];    // [w][d][q] +1 pad        34.8 KB
  __shared__ float Ls[8][16];
  __shared__ u16  Pl[8][16][68];     // [w][q][kv] +4 pad       17.4 KB
  const int tid = threadIdx.x;
  const int lane = tid & 63, w = tid >> 6;
  const int c16 = lane & 15, quad = lane >> 4;
  const int b = blockIdx.y;
  const int q0 = blockIdx.x * 16;

  // Q B-frags (n=q=c16, k=d contiguous), persistent
  bf16x8 qf[2];
  {
    const u16* qp = qh + (size_t)(b * 2048 + q0 + c16) * 64 + quad * 8;
    qf[0] = *(const bf16x8*)qp;
    qf[1] = *(const bf16x8*)(qp + 32);
  }
  const float fscale = 0.125f * m[b * 2048 + q0 + c16];

  f32x4 oacc[4];
#pragma unroll
  for (int nt = 0; nt < 4; nt++)
#pragma unroll
    for (int j = 0; j < 4; j++) oacc[nt][j] = 0.0f;
  float lsum = 0.0f;

  const u16* kb = kh + (size_t)b * 131072;
  const u16* vb = vhT + (size_t)b * 131072;

  for (int c = 0; c < 4; c++) {
    const int kv0 = w * 64 + c * 512;
    // ---- S^T = K Q^T ----
    f32x4 sacc[4];
#pragma unroll
    for (int nt = 0; nt < 4; nt++)
#pragma unroll
      for (int j = 0; j < 4; j++) sacc[nt][j] = 0.0f;
#pragma unroll
    for (int ks = 0; ks < 2; ks++)
#pragma unroll
      for (int nt = 0; nt < 4; nt++) {
        bf16x8 kf = *(const bf16x8*)(kb + (size_t)(kv0 + nt * 16 + c16) * 64 + ks * 32 + quad * 8);
        sacc[nt] = __builtin_amdgcn_mfma_f32_16x16x32_bf16(kf, qf[ks], sacc[nt], 0, 0, 0);
      }
    // ---- prefetch V A-frags for ks2=0 (fly during softmax) ----
    bf16x8 vf0[4];
#pragma unroll
    for (int nt = 0; nt < 4; nt++)
      vf0[nt] = *(const bf16x8*)(vb + (size_t)(nt * 16 + c16) * 2048 + kv0 + quad * 8);
    // ---- p = exp(m*s/8); per-lane l partial (no max: |s*m/8| small) ----
#pragma unroll
    for (int nt = 0; nt < 4; nt++)
#pragma unroll
      for (int rr = 0; rr < 4; rr++) {
        float p = __expf(sacc[nt][rr] * fscale);
        sacc[nt][rr] = p;
        lsum += p;
      }
    // ---- pack P^T rows: lane holds P[q=c16][kv=nt*16+quad*4+rr] ----
#pragma unroll
    for (int nt = 0; nt < 4; nt++) {
      ushort4 pk = make_ushort4(f2bf(sacc[nt][0]), f2bf(sacc[nt][1]),
                                f2bf(sacc[nt][2]), f2bf(sacc[nt][3]));
      *(ushort4*)&Pl[w][c16][nt * 16 + quad * 4] = pk;
    }
    // ---- O^T += V^T P^T (wave-private LDS, DS in-order; no barrier) ----
    bf16x8 vf1[4];
#pragma unroll
    for (int nt = 0; nt < 4; nt++)
      vf1[nt] = *(const bf16x8*)(vb + (size_t)(nt * 16 + c16) * 2048 + kv0 + 32 + quad * 8);
    {
      bf16x8 pf = *(const bf16x8*)&Pl[w][c16][quad * 8];
#pragma unroll
      for (int nt = 0; nt < 4; nt++)
        oacc[nt] = __builtin_amdgcn_mfma_f32_16x16x32_bf16(vf0[nt], pf, oacc[nt], 0, 0, 0);
    }
    {
      bf16x8 pf = *(const bf16x8*)&Pl[w][c16][32 + quad * 8];
#pragma unroll
      for (int nt = 0; nt < 4; nt++)
        oacc[nt] = __builtin_amdgcn_mfma_f32_16x16x32_bf16(vf1[nt], pf, oacc[nt], 0, 0, 0);
    }
  }

  // ---- l: sum the 4 lanes sharing c16 (quads) ----
  lsum += __shfl_xor(lsum, 16);
  lsum += __shfl_xor(lsum, 32);

  // ---- publish partials, combine across kv-split ----
#pragma unroll
  for (int nt = 0; nt < 4; nt++)
#pragma unroll
    for (int rr = 0; rr < 4; rr++)
      Os[w][nt * 16 + quad * 4 + rr][c16] = oacc[nt][rr];
  if (quad == 0) Ls[w][c16] = lsum;
  __syncthreads();

#pragma unroll
  for (int e = tid; e < 1024; e += 512) {
    const int qq = e >> 6, d = e & 63;
    float s = 0.0f, l = 0.0f;
#pragma unroll
    for (int ww = 0; ww < 8; ww++) { s += Os[ww][d][qq]; l += Ls[ww][qq]; }
    y[(size_t)(b * 2048 + q0 + qq) * 64 + d] = s / l;
  }
}

// ---------------------------------------------------------------------------
extern "C" void kernel_launch(void* const* d_in, const int* in_sizes, int n_in,
                              void* d_out, int out_size, void* d_ws, size_t ws_size,
                              hipStream_t stream) {
  (void)in_sizes; (void)n_in; (void)out_size; (void)ws_size;
  const float* q  = (const float*)d_in[0];
  const float* k  = (const float*)d_in[1];
  const float* v  = (const float*)d_in[2];
  const float* m  = (const float*)d_in[3];
  const float* Wq = (const float*)d_in[4];
  const float* Wk = (const float*)d_in[5];
  const float* Wv = (const float*)d_in[6];
  float* y = (float*)d_out;

  u16* qh  = (u16*)d_ws;          // [4][2048][64] bf16  (1 MB)
  u16* kh  = qh + 524288;         // [4][2048][64] bf16  (1 MB)
  u16* vhT = kh + 524288;         // [4][64][2048] bf16  (1 MB)
  u16* Wbf = vhT + 524288;        // [3][64][1024] bf16  (384 KB)

  wcvt_kernel<<<dim3(192), 256, 0, stream>>>(Wq, Wk, Wv, Wbf);
  proj_kernel<<<dim3(512, 3), 256, 0, stream>>>(q, k, v, Wbf, qh, kh, vhT);
  attn_kernel<<<dim3(128, 4), 512, 0, stream>>>(qh, kh, vhT, m, y);
}

// Round 7
// 169.817 us; speedup vs baseline: 1.0809x; 1.0809x over previous
//
#include <hip/hip_runtime.h>
#include <stdint.h>

// ---------------------------------------------------------------------------
// MaskedAttentionHead: B=4, S=2048, d_model=1024, d_k=64
// R7: proj rebuilt for guaranteed memory-level parallelism. R2/R3/R6 all
// died to compiler register-minimization (VGPR 16/44/32 -> ~1 load in
// flight); R4/R5 died to glds per-wave serialization. Now: wave owns 16
// rows x full K (acc carried, zero combine); X loaded in bursts of 16
// float4 into 64 named VGPRs (first use = pack8 of the whole burst ->
// unsinkable); W served from a 65-KB LDS half-panel (stride 520 = uniform
// bank groups), reloaded once at half-K; launch_bounds(256,2) = 256-VGPR
// budget. 384 blocks x 256 thr, 2 blocks/CU, 3 barriers per block.
// attn/wcvt unchanged (attn still unprofiled).
// ---------------------------------------------------------------------------

typedef __bf16 bf16x8 __attribute__((ext_vector_type(8)));
typedef float  f32x4  __attribute__((ext_vector_type(4)));
typedef unsigned short u16;
typedef unsigned int   u32;

__device__ __forceinline__ u16 f2bf(float f) {
  u32 u = __float_as_uint(f);
  u += 0x7fffu + ((u >> 16) & 1u);          // round-to-nearest-even
  return (u16)(u >> 16);
}

union BF8 { bf16x8 v; u16 u[8]; };

__device__ __forceinline__ bf16x8 pack8(float4 a, float4 b) {
  BF8 r;
  r.u[0] = f2bf(a.x); r.u[1] = f2bf(a.y); r.u[2] = f2bf(a.z); r.u[3] = f2bf(a.w);
  r.u[4] = f2bf(b.x); r.u[5] = f2bf(b.y); r.u[6] = f2bf(b.z); r.u[7] = f2bf(b.w);
  return r.v;
}

// --------------------------- W fp32 -> bf16 --------------------------------
__global__ __launch_bounds__(256) void wcvt_kernel(
    const float* __restrict__ Wq, const float* __restrict__ Wk,
    const float* __restrict__ Wv, u16* __restrict__ Wbf) {
  int i = (blockIdx.x * 256 + threadIdx.x) * 4;   // 3*64*1024 = 196608 total
  const float* src = (i < 65536) ? Wq : (i < 131072) ? Wk : Wv;
  int off = i & 65535;
  float4 f = *(const float4*)(src + off);
  *(ushort4*)(Wbf + i) = make_ushort4(f2bf(f.x), f2bf(f.y), f2bf(f.z), f2bf(f.w));
}

// --------------------------- projections -----------------------------------
// grid 384 (which = bx%3, 128 row-blocks/which), block 256 (4 waves x 16
// rows), 2 blocks/CU. K processed in 2 halves (W half-panel 64x512 bf16 in
// LDS, stride 520 u16 -> addr/16 %8 = (row+seg)%8 = uniform bank groups);
// per half, 2 A-bursts of 16 float4 (k=256) with next-burst issue between
// pack and MFMA. acc carried across all 4 bursts -> no combine, wave-private
// epilogue.
__global__ __launch_bounds__(256, 2) void proj_kernel(
    const float* __restrict__ q, const float* __restrict__ k,
    const float* __restrict__ v, const u16* __restrict__ Wbf,
    u16* __restrict__ qh, u16* __restrict__ kh, u16* __restrict__ vhT) {
  __shared__ u16 wl[64 * 520];               // 66.6 KB half-panel
  const int tid = threadIdx.x;
  const int lane = tid & 63, w = tid >> 6;
  const int c16 = lane & 15, quad = lane >> 4;
  const int which = blockIdx.x % 3;
  const int rblk = blockIdx.x / 3;           // 0..127
  const int r0 = rblk * 64 + w * 16;         // wave's 16 rows (global b*S+s)
  const float* X = (which == 0) ? q : (which == 1) ? k : v;
  const u16* wsrc = Wbf + which * 65536;

  const float* xp = X + (size_t)(r0 + c16) * 1024 + quad * 8;

  // ---- burst 0: 16 float4 into named regs (16 KB/wave in flight) ----
  float4 ar[16];
#pragma unroll
  for (int i = 0; i < 8; i++) {
    ar[2 * i]     = *(const float4*)(xp + i * 32);
    ar[2 * i + 1] = *(const float4*)(xp + i * 32 + 4);
  }

  f32x4 acc[4];
#pragma unroll
  for (int nt = 0; nt < 4; nt++)
#pragma unroll
    for (int j = 0; j < 4; j++) acc[nt][j] = 0.0f;

#pragma unroll
  for (int h = 0; h < 2; h++) {
    if (h) __syncthreads();                  // wl reuse safe
    // ---- preload W half h: coalesced 1-KB reads -> strided LDS ----
#pragma unroll
    for (int i = 0; i < 16; i++) {
      int flat = i * 2048 + tid * 8;         // 32768 u16 per half
      int row = flat >> 9, col = flat & 511;
      *(bf16x8*)(wl + row * 520 + col) =
          *(const bf16x8*)(wsrc + (size_t)row * 1024 + h * 512 + col);
    }
    __syncthreads();

#pragma unroll
    for (int cb = 0; cb < 2; cb++) {
      const int kb0 = h * 512 + cb * 256;    // this burst's k-base (loaded)
      // consume whole burst into bf16 frags (single use point -> unsinkable)
      bf16x8 af[8];
#pragma unroll
      for (int i = 0; i < 8; i++) af[i] = pack8(ar[2 * i], ar[2 * i + 1]);
      // issue next burst (flies during the 32 MFMAs below)
      if (kb0 < 768) {
#pragma unroll
        for (int i = 0; i < 8; i++) {
          ar[2 * i]     = *(const float4*)(xp + kb0 + 256 + i * 32);
          ar[2 * i + 1] = *(const float4*)(xp + kb0 + 256 + i * 32 + 4);
        }
      }
      // ---- 8 k-steps x 4 n-tiles; W frags from LDS ----
#pragma unroll
      for (int ks = 0; ks < 8; ks++)
#pragma unroll
        for (int nt = 0; nt < 4; nt++) {
          bf16x8 wf = *(const bf16x8*)(wl + (nt * 16 + c16) * 520 +
                                       cb * 256 + ks * 32 + quad * 8);
          acc[nt] = __builtin_amdgcn_mfma_f32_16x16x32_bf16(af[ks], wf, acc[nt], 0, 0, 0);
        }
    }
  }

  // ---- wave-private epilogue (C/D: row=quad*4+rr, col=nt*16+c16) ----
  if (which == 2) {
    const int bb = r0 >> 11, s0 = (r0 & 2047) + quad * 4;
#pragma unroll
    for (int nt = 0; nt < 4; nt++) {
      ushort4 pk = make_ushort4(f2bf(acc[nt][0]), f2bf(acc[nt][1]),
                                f2bf(acc[nt][2]), f2bf(acc[nt][3]));
      *(ushort4*)(vhT + ((size_t)bb * 64 + nt * 16 + c16) * 2048 + s0) = pk;
    }
  } else {
    u16* out = (which == 0) ? qh : kh;
#pragma unroll
    for (int nt = 0; nt < 4; nt++)
#pragma unroll
      for (int rr = 0; rr < 4; rr++)
        out[(size_t)(r0 + quad * 4 + rr) * 64 + nt * 16 + c16] = f2bf(acc[nt][rr]);
  }
}

// --------------------------- flash attention --------------------------------
// grid (128,4), block 512 (8 waves, kv-split 8). Transposed math:
//   S^T[kv][q] = K Q^T  (A=K-frag, B=Q-frag, both natural row-major)
//   O^T[d][q]  = V^T P^T (A=vhT-frag, B=P-frag from packed LDS)
// Mask scale is per-column q = c16 -> one scalar/lane. No kv-loop barriers.
__global__ __launch_bounds__(512, 4) void attn_kernel(
    const u16* __restrict__ qh, const u16* __restrict__ kh,
    const u16* __restrict__ vhT, const float* __restrict__ m,
    float* __restrict__ y) {
  __shared__ float Os[8][64][17];    // [w][d][q] +1 pad        34.8 KB
  __shared__ float Ls[8][16];
  __shared__ u16  Pl[8][16][68];     // [w][q][kv] +4 pad       17.4 KB
  const int tid = threadIdx.x;
  const int lane = tid & 63, w = tid >> 6;
  const int c16 = lane & 15, quad = lane >> 4;
  const int b = blockIdx.y;
  const int q0 = blockIdx.x * 16;

  // Q B-frags (n=q=c16, k=d contiguous), persistent
  bf16x8 qf[2];
  {
    const u16* qp = qh + (size_t)(b * 2048 + q0 + c16) * 64 + quad * 8;
    qf[0] = *(const bf16x8*)qp;
    qf[1] = *(const bf16x8*)(qp + 32);
  }
  const float fscale = 0.125f * m[b * 2048 + q0 + c16];

  f32x4 oacc[4];
#pragma unroll
  for (int nt = 0; nt < 4; nt++)
#pragma unroll
    for (int j = 0; j < 4; j++) oacc[nt][j] = 0.0f;
  float lsum = 0.0f;

  const u16* kb = kh + (size_t)b * 131072;
  const u16* vb = vhT + (size_t)b * 131072;

  for (int c = 0; c < 4; c++) {
    const int kv0 = w * 64 + c * 512;
    // ---- S^T = K Q^T ----
    f32x4 sacc[4];
#pragma unroll
    for (int nt = 0; nt < 4; nt++)
#pragma unroll
      for (int j = 0; j < 4; j++) sacc[nt][j] = 0.0f;
#pragma unroll
    for (int ks = 0; ks < 2; ks++)
#pragma unroll
      for (int nt = 0; nt < 4; nt++) {
        bf16x8 kf = *(const bf16x8*)(kb + (size_t)(kv0 + nt * 16 + c16) * 64 + ks * 32 + quad * 8);
        sacc[nt] = __builtin_amdgcn_mfma_f32_16x16x32_bf16(kf, qf[ks], sacc[nt], 0, 0, 0);
      }
    // ---- prefetch V A-frags for ks2=0 (fly during softmax) ----
    bf16x8 vf0[4];
#pragma unroll
    for (int nt = 0; nt < 4; nt++)
      vf0[nt] = *(const bf16x8*)(vb + (size_t)(nt * 16 + c16) * 2048 + kv0 + quad * 8);
    // ---- p = exp(m*s/8); per-lane l partial (no max: |s*m/8| small) ----
#pragma unroll
    for (int nt = 0; nt < 4; nt++)
#pragma unroll
      for (int rr = 0; rr < 4; rr++) {
        float p = __expf(sacc[nt][rr] * fscale);
        sacc[nt][rr] = p;
        lsum += p;
      }
    // ---- pack P^T rows: lane holds P[q=c16][kv=nt*16+quad*4+rr] ----
#pragma unroll
    for (int nt = 0; nt < 4; nt++) {
      ushort4 pk = make_ushort4(f2bf(sacc[nt][0]), f2bf(sacc[nt][1]),
                                f2bf(sacc[nt][2]), f2bf(sacc[nt][3]));
      *(ushort4*)&Pl[w][c16][nt * 16 + quad * 4] = pk;
    }
    // ---- O^T += V^T P^T (wave-private LDS, DS in-order; no barrier) ----
    bf16x8 vf1[4];
#pragma unroll
    for (int nt = 0; nt < 4; nt++)
      vf1[nt] = *(const bf16x8*)(vb + (size_t)(nt * 16 + c16) * 2048 + kv0 + 32 + quad * 8);
    {
      bf16x8 pf = *(const bf16x8*)&Pl[w][c16][quad * 8];
#pragma unroll
      for (int nt = 0; nt < 4; nt++)
        oacc[nt] = __builtin_amdgcn_mfma_f32_16x16x32_bf16(vf0[nt], pf, oacc[nt], 0, 0, 0);
    }
    {
      bf16x8 pf = *(const bf16x8*)&Pl[w][c16][32 + quad * 8];
#pragma unroll
      for (int nt = 0; nt < 4; nt++)
        oacc[nt] = __builtin_amdgcn_mfma_f32_16x16x32_bf16(vf1[nt], pf, oacc[nt], 0, 0, 0);
    }
  }

  // ---- l: sum the 4 lanes sharing c16 (quads) ----
  lsum += __shfl_xor(lsum, 16);
  lsum += __shfl_xor(lsum, 32);

  // ---- publish partials, combine across kv-split ----
#pragma unroll
  for (int nt = 0; nt < 4; nt++)
#pragma unroll
    for (int rr = 0; rr < 4; rr++)
      Os[w][nt * 16 + quad * 4 + rr][c16] = oacc[nt][rr];
  if (quad == 0) Ls[w][c16] = lsum;
  __syncthreads();

#pragma unroll
  for (int e = tid; e < 1024; e += 512) {
    const int qq = e >> 6, d = e & 63;
    float s = 0.0f, l = 0.0f;
#pragma unroll
    for (int ww = 0; ww < 8; ww++) { s += Os[ww][d][qq]; l += Ls[ww][qq]; }
    y[(size_t)(b * 2048 + q0 + qq) * 64 + d] = s / l;
  }
}

// ---------------------------------------------------------------------------
extern "C" void kernel_launch(void* const* d_in, const int* in_sizes, int n_in,
                              void* d_out, int out_size, void* d_ws, size_t ws_size,
                              hipStream_t stream) {
  (void)in_sizes; (void)n_in; (void)out_size; (void)ws_size;
  const float* q  = (const float*)d_in[0];
  const float* k  = (const float*)d_in[1];
  const float* v  = (const float*)d_in[2];
  const float* m  = (const float*)d_in[3];
  const float* Wq = (const float*)d_in[4];
  const float* Wk = (const float*)d_in[5];
  const float* Wv = (const float*)d_in[6];
  float* y = (float*)d_out;

  u16* qh  = (u16*)d_ws;          // [4][2048][64] bf16  (1 MB)
  u16* kh  = qh + 524288;         // [4][2048][64] bf16  (1 MB)
  u16* vhT = kh + 524288;         // [4][64][2048] bf16  (1 MB)
  u16* Wbf = vhT + 524288;        // [3][64][1024] bf16  (384 KB)

  wcvt_kernel<<<dim3(192), 256, 0, stream>>>(Wq, Wk, Wv, Wbf);
  proj_kernel<<<dim3(384), 256, 0, stream>>>(q, k, v, Wbf, qh, kh, vhT);
  attn_kernel<<<dim3(128, 4), 512, 0, stream>>>(qh, kh, vhT, m, y);
}

// Round 8
// 168.665 us; speedup vs baseline: 1.0883x; 1.0068x over previous
//
#include <hip/hip_runtime.h>
#include <stdint.h>

// ---------------------------------------------------------------------------
// MaskedAttentionHead: B=4, S=2048, d_model=1024, d_k=64
// R8: proj global reads are now PURE STREAMING (the one config never tried:
// contiguous AND parallel). Evidence: every MFMA-lane-pattern loader stalled
// at ~2.3 TB/s consumed (R2-R7) while contiguous kernels (harness fill,
// m13 copy) hit 6.3+. Wave bursts its 4 X rows as 16 contiguous 1-KB float4
// loads into named regs (held: R7 proved bounds(256,2) keeps them), cvt ->
// LDS; A and W frags both read from padded LDS (2-way = free). K-split 4
// ways, W in 34-KB quarter-panels restaged between barriers, R6's verified
// combine epilogue overlaid on the dead X tile. 67 KB LDS -> 2 blocks/CU.
// attn/wcvt unchanged from R7 (attn still unprofiled).
// ---------------------------------------------------------------------------

typedef __bf16 bf16x8 __attribute__((ext_vector_type(8)));
typedef float  f32x4  __attribute__((ext_vector_type(4)));
typedef unsigned short u16;
typedef unsigned int   u32;

__device__ __forceinline__ u16 f2bf(float f) {
  u32 u = __float_as_uint(f);
  u += 0x7fffu + ((u >> 16) & 1u);          // round-to-nearest-even
  return (u16)(u >> 16);
}

// --------------------------- W fp32 -> bf16 --------------------------------
__global__ __launch_bounds__(256) void wcvt_kernel(
    const float* __restrict__ Wq, const float* __restrict__ Wk,
    const float* __restrict__ Wv, u16* __restrict__ Wbf) {
  int i = (blockIdx.x * 256 + threadIdx.x) * 4;   // 3*64*1024 = 196608 total
  const float* src = (i < 65536) ? Wq : (i < 131072) ? Wk : Wv;
  int off = i & 65535;
  float4 f = *(const float4*)(src + off);
  *(ushort4*)(Wbf + i) = make_ushort4(f2bf(f.x), f2bf(f.y), f2bf(f.z), f2bf(f.w));
}

// --------------------------- projections -----------------------------------
// grid 1536 (which = bx%3, 512 row-blocks), block 256 (4 waves), 2 blocks/CU.
// Block owns 16 rows. Wave w stages rows w*4..w*4+3 (16 contiguous float4
// loads -> 64 named VGPRs -> cvt -> LDS) and computes k-slice
// {qq*256 + w*64 .. +64} for qq=0..3 (acc carried). W quarter-panel 64x256
// bf16 in LDS, restaged per qq. Combine 4 k-partials via os overlay on xl.
__global__ __launch_bounds__(256, 2) void proj_kernel(
    const float* __restrict__ q, const float* __restrict__ k,
    const float* __restrict__ v, const u16* __restrict__ Wbf,
    u16* __restrict__ qh, u16* __restrict__ kh, u16* __restrict__ vhT) {
  __shared__ u16 xl[16][1032];   // X tile bf16; stride 2064 B -> 2-way (free)
  __shared__ u16 wq[64][264];    // W quarter;  stride  528 B -> 2-way (free)
  const int tid = threadIdx.x;
  const int lane = tid & 63, w = tid >> 6;
  const int c16 = lane & 15, quad = lane >> 4;
  const int which = blockIdx.x % 3;
  const int r0 = (blockIdx.x / 3) * 16;
  const float* X = (which == 0) ? q : (which == 1) ? k : v;
  const u16* wsrc = Wbf + which * 65536;

  // ---- issue W quarter-0 loads first (oldest -> retire before X burst) ----
  bf16x8 wld[8];
#pragma unroll
  for (int i = 0; i < 8; i++) {
    int f = i * 2048 + tid * 8;              // 16384 u16 = 64 x 256
    wld[i] = *(const bf16x8*)(wsrc + (size_t)(f >> 8) * 1024 + (f & 255));
  }
  // ---- X burst: 16 contiguous 1-KB float4 loads (wave's 4 rows) ----
  const float* xgw = X + (size_t)(r0 + w * 4) * 1024 + lane * 4;
  float4 ar[16];
#pragma unroll
  for (int i = 0; i < 16; i++) ar[i] = *(const float4*)(xgw + i * 256);

  // ---- W q0 -> LDS (waits only the 8 W loads: vmcnt(16)) ----
#pragma unroll
  for (int i = 0; i < 8; i++) {
    int f = i * 2048 + tid * 8;
    *(bf16x8*)&wq[f >> 8][f & 255] = wld[i];
  }
  // ---- X cvt -> LDS (waits vmcnt(0)) ----
#pragma unroll
  for (int i = 0; i < 16; i++) {
    ushort4 pk = make_ushort4(f2bf(ar[i].x), f2bf(ar[i].y),
                              f2bf(ar[i].z), f2bf(ar[i].w));
    *(ushort4*)&xl[w * 4 + (i >> 2)][(i & 3) * 256 + lane * 4] = pk;
  }
  __syncthreads();

  f32x4 acc[4];
#pragma unroll
  for (int nt = 0; nt < 4; nt++)
#pragma unroll
    for (int j = 0; j < 4; j++) acc[nt][j] = 0.0f;

#pragma unroll
  for (int qq = 0; qq < 4; qq++) {
    // ---- compute this quarter: wave's 64-wide k-slice, 8 MFMA ----
#pragma unroll
    for (int ks = 0; ks < 2; ks++) {
      const int kin = w * 64 + ks * 32 + quad * 8;       // col within quarter
      bf16x8 af = *(const bf16x8*)&xl[c16][qq * 256 + kin];
#pragma unroll
      for (int nt = 0; nt < 4; nt++) {
        bf16x8 wf = *(const bf16x8*)&wq[nt * 16 + c16][kin];
        acc[nt] = __builtin_amdgcn_mfma_f32_16x16x32_bf16(af, wf, acc[nt], 0, 0, 0);
      }
    }
    // ---- restage W quarter qq+1 ----
    if (qq < 3) {
      __syncthreads();                       // all waves done reading wq
#pragma unroll
      for (int i = 0; i < 8; i++) {
        int f = i * 2048 + tid * 8;
        *(bf16x8*)&wq[f >> 8][f & 255] =
            *(const bf16x8*)(wsrc + (size_t)(f >> 8) * 1024 + (qq + 1) * 256 + (f & 255));
      }
      __syncthreads();
    }
  }

  // ---- combine 4 k-partials via os overlay on xl (xl dead) ----
  __syncthreads();
  float* osp = (float*)&xl[0][0];            // os[w][16][64] = 16 KB
#pragma unroll
  for (int nt = 0; nt < 4; nt++)
#pragma unroll
    for (int rr = 0; rr < 4; rr++)
      osp[((size_t)w * 16 + quad * 4 + rr) * 64 + nt * 16 + c16] = acc[nt][rr];
  __syncthreads();

  if (which == 2) {
    const int col = tid >> 2, s4 = (tid & 3) * 4;
    float s[4];
#pragma unroll
    for (int rr = 0; rr < 4; rr++)
      s[rr] = osp[(0 * 16 + s4 + rr) * 64 + col] + osp[(1 * 16 + s4 + rr) * 64 + col] +
              osp[(2 * 16 + s4 + rr) * 64 + col] + osp[(3 * 16 + s4 + rr) * 64 + col];
    const int bb = r0 >> 11, s0 = (r0 & 2047) + s4;
    ushort4 pk = make_ushort4(f2bf(s[0]), f2bf(s[1]), f2bf(s[2]), f2bf(s[3]));
    *(ushort4*)(vhT + ((size_t)bb * 64 + col) * 2048 + s0) = pk;
  } else {
    u16* out = (which == 0) ? qh : kh;
    const int row = tid >> 4, c4 = (tid & 15) * 4;
    float s[4];
#pragma unroll
    for (int j = 0; j < 4; j++)
      s[j] = osp[(0 * 16 + row) * 64 + c4 + j] + osp[(1 * 16 + row) * 64 + c4 + j] +
             osp[(2 * 16 + row) * 64 + c4 + j] + osp[(3 * 16 + row) * 64 + c4 + j];
    ushort4 pk = make_ushort4(f2bf(s[0]), f2bf(s[1]), f2bf(s[2]), f2bf(s[3]));
    *(ushort4*)(out + (size_t)(r0 + row) * 64 + c4) = pk;
  }
}

// --------------------------- flash attention --------------------------------
// grid (128,4), block 512 (8 waves, kv-split 8). Transposed math:
//   S^T[kv][q] = K Q^T  (A=K-frag, B=Q-frag, both natural row-major)
//   O^T[d][q]  = V^T P^T (A=vhT-frag, B=P-frag from packed LDS)
// Mask scale is per-column q = c16 -> one scalar/lane. No kv-loop barriers.
__global__ __launch_bounds__(512, 4) void attn_kernel(
    const u16* __restrict__ qh, const u16* __restrict__ kh,
    const u16* __restrict__ vhT, const float* __restrict__ m,
    float* __restrict__ y) {
  __shared__ float Os[8][64][17];    // [w][d][q] +1 pad        34.8 KB
  __shared__ float Ls[8][16];
  __shared__ u16  Pl[8][16][68];     // [w][q][kv] +4 pad       17.4 KB
  const int tid = threadIdx.x;
  const int lane = tid & 63, w = tid >> 6;
  const int c16 = lane & 15, quad = lane >> 4;
  const int b = blockIdx.y;
  const int q0 = blockIdx.x * 16;

  // Q B-frags (n=q=c16, k=d contiguous), persistent
  bf16x8 qf[2];
  {
    const u16* qp = qh + (size_t)(b * 2048 + q0 + c16) * 64 + quad * 8;
    qf[0] = *(const bf16x8*)qp;
    qf[1] = *(const bf16x8*)(qp + 32);
  }
  const float fscale = 0.125f * m[b * 2048 + q0 + c16];

  f32x4 oacc[4];
#pragma unroll
  for (int nt = 0; nt < 4; nt++)
#pragma unroll
    for (int j = 0; j < 4; j++) oacc[nt][j] = 0.0f;
  float lsum = 0.0f;

  const u16* kb = kh + (size_t)b * 131072;
  const u16* vb = vhT + (size_t)b * 131072;

  for (int c = 0; c < 4; c++) {
    const int kv0 = w * 64 + c * 512;
    // ---- S^T = K Q^T ----
    f32x4 sacc[4];
#pragma unroll
    for (int nt = 0; nt < 4; nt++)
#pragma unroll
      for (int j = 0; j < 4; j++) sacc[nt][j] = 0.0f;
#pragma unroll
    for (int ks = 0; ks < 2; ks++)
#pragma unroll
      for (int nt = 0; nt < 4; nt++) {
        bf16x8 kf = *(const bf16x8*)(kb + (size_t)(kv0 + nt * 16 + c16) * 64 + ks * 32 + quad * 8);
        sacc[nt] = __builtin_amdgcn_mfma_f32_16x16x32_bf16(kf, qf[ks], sacc[nt], 0, 0, 0);
      }
    // ---- prefetch V A-frags for ks2=0 (fly during softmax) ----
    bf16x8 vf0[4];
#pragma unroll
    for (int nt = 0; nt < 4; nt++)
      vf0[nt] = *(const bf16x8*)(vb + (size_t)(nt * 16 + c16) * 2048 + kv0 + quad * 8);
    // ---- p = exp(m*s/8); per-lane l partial (no max: |s*m/8| small) ----
#pragma unroll
    for (int nt = 0; nt < 4; nt++)
#pragma unroll
      for (int rr = 0; rr < 4; rr++) {
        float p = __expf(sacc[nt][rr] * fscale);
        sacc[nt][rr] = p;
        lsum += p;
      }
    // ---- pack P^T rows: lane holds P[q=c16][kv=nt*16+quad*4+rr] ----
#pragma unroll
    for (int nt = 0; nt < 4; nt++) {
      ushort4 pk = make_ushort4(f2bf(sacc[nt][0]), f2bf(sacc[nt][1]),
                                f2bf(sacc[nt][2]), f2bf(sacc[nt][3]));
      *(ushort4*)&Pl[w][c16][nt * 16 + quad * 4] = pk;
    }
    // ---- O^T += V^T P^T (wave-private LDS, DS in-order; no barrier) ----
    bf16x8 vf1[4];
#pragma unroll
    for (int nt = 0; nt < 4; nt++)
      vf1[nt] = *(const bf16x8*)(vb + (size_t)(nt * 16 + c16) * 2048 + kv0 + 32 + quad * 8);
    {
      bf16x8 pf = *(const bf16x8*)&Pl[w][c16][quad * 8];
#pragma unroll
      for (int nt = 0; nt < 4; nt++)
        oacc[nt] = __builtin_amdgcn_mfma_f32_16x16x32_bf16(vf0[nt], pf, oacc[nt], 0, 0, 0);
    }
    {
      bf16x8 pf = *(const bf16x8*)&Pl[w][c16][32 + quad * 8];
#pragma unroll
      for (int nt = 0; nt < 4; nt++)
        oacc[nt] = __builtin_amdgcn_mfma_f32_16x16x32_bf16(vf1[nt], pf, oacc[nt], 0, 0, 0);
    }
  }

  // ---- l: sum the 4 lanes sharing c16 (quads) ----
  lsum += __shfl_xor(lsum, 16);
  lsum += __shfl_xor(lsum, 32);

  // ---- publish partials, combine across kv-split ----
#pragma unroll
  for (int nt = 0; nt < 4; nt++)
#pragma unroll
    for (int rr = 0; rr < 4; rr++)
      Os[w][nt * 16 + quad * 4 + rr][c16] = oacc[nt][rr];
  if (quad == 0) Ls[w][c16] = lsum;
  __syncthreads();

#pragma unroll
  for (int e = tid; e < 1024; e += 512) {
    const int qq = e >> 6, d = e & 63;
    float s = 0.0f, l = 0.0f;
#pragma unroll
    for (int ww = 0; ww < 8; ww++) { s += Os[ww][d][qq]; l += Ls[ww][qq]; }
    y[(size_t)(b * 2048 + q0 + qq) * 64 + d] = s / l;
  }
}

// ---------------------------------------------------------------------------
extern "C" void kernel_launch(void* const* d_in, const int* in_sizes, int n_in,
                              void* d_out, int out_size, void* d_ws, size_t ws_size,
                              hipStream_t stream) {
  (void)in_sizes; (void)n_in; (void)out_size; (void)ws_size;
  const float* q  = (const float*)d_in[0];
  const float* k  = (const float*)d_in[1];
  const float* v  = (const float*)d_in[2];
  const float* m  = (const float*)d_in[3];
  const float* Wq = (const float*)d_in[4];
  const float* Wk = (const float*)d_in[5];
  const float* Wv = (const float*)d_in[6];
  float* y = (float*)d_out;

  u16* qh  = (u16*)d_ws;          // [4][2048][64] bf16  (1 MB)
  u16* kh  = qh + 524288;         // [4][2048][64] bf16  (1 MB)
  u16* vhT = kh + 524288;         // [4][64][2048] bf16  (1 MB)
  u16* Wbf = vhT + 524288;        // [3][64][1024] bf16  (384 KB)

  wcvt_kernel<<<dim3(192), 256, 0, stream>>>(Wq, Wk, Wv, Wbf);
  proj_kernel<<<dim3(1536), 256, 0, stream>>>(q, k, v, Wbf, qh, kh, vhT);
  attn_kernel<<<dim3(128, 4), 512, 0, stream>>>(qh, kh, vhT, m, y);
}